// Round 7
// baseline (132.750 us; speedup 1.0000x reference)
//
#include <hip/hip_runtime.h>
#include <hip/hip_bf16.h>
#include <stdint.h>

typedef short bf16x8 __attribute__((ext_vector_type(8)));
typedef float f32x16 __attribute__((ext_vector_type(16)));

#define N_IMG 16
#define C_IN  128
#define H_IMG 64
#define W_IMG 64
#define K_OUT 256

// ws layout: xb = padded NHWC bf16 [16][66][66][128]; wb2 = frag-ordered W bf16:
//   [chunk=tap*4+cc (36)][kgrp (8)][ks (2)][lane (64)][8 bf16]   (16 KB per chunk)
#define XB_BYTES (16ull*66*66*128*2)       // 17,842,176
#define WB_BYTES (36ull*8*2*64*16)         //    589,824
#define WS_NEED  (XB_BYTES + WB_BYTES)

#define LDSX_BYTES (4*66*256)              // 67,584 (X tile: 2 out-rows + halo)

__device__ __forceinline__ void gload16(void* lds, const void* g) {
    __builtin_amdgcn_global_load_lds(
        (const __attribute__((address_space(1))) void*)g,
        (__attribute__((address_space(3))) void*)lds, 16, 0, 0);
}

__device__ __forceinline__ uint32_t pack2(float a, float b) {
    __hip_bfloat16 ha = __float2bfloat16(a), hb = __float2bfloat16(b);
    return (uint32_t)*(uint16_t*)&ha | ((uint32_t)*(uint16_t*)&hb << 16);
}

// ---------------- fused prep: x -> padded NHWC bf16, w -> frag-ordered wb2 ------------
// blocks [0,1056): x rows.  blocks [1056,1312): w out-channel groups (one k each).
__global__ __launch_bounds__(256)
void transform_fused_kernel(const float* __restrict__ x, const float* __restrict__ w,
                            __hip_bfloat16* __restrict__ xb, __hip_bfloat16* __restrict__ wb) {
    __shared__ __align__(16) uint32_t xs[64 * 64];   // [row=x][cpair j], XOR-swizzled
    __shared__ float lw[1152];
    const int b = blockIdx.x;
    const int t = threadIdx.x;

    if (b < 1056) {
        const int yt = b % 66;
        const int n  = b / 66;
        const bool interior = (yt >= 1 && yt <= 64);

        if (interior) {
            const float4* src = (const float4*)(x + (size_t)n * 524288 + (size_t)(yt - 1) * 64);
            #pragma unroll
            for (int it = 0; it < 4; ++it) {
                const int x4 = t & 15;                 // float4 index in row (coalesced)
                const int j  = (t >> 4) + it * 16;     // c-pair 0..63
                float4 va = src[(2 * j) * 1024 + x4];
                float4 vb = src[(2 * j + 1) * 1024 + x4];
                const float* pa = (const float*)&va;
                const float* pb = (const float*)&vb;
                #pragma unroll
                for (int i = 0; i < 4; ++i) {
                    int row = x4 * 4 + i;
                    xs[row * 64 + (j ^ (((row >> 2) & 3) << 2))] = pack2(pa[i], pb[i]);
                }
            }
        }
        __syncthreads();

        uint4* dst = (uint4*)((char*)xb + (size_t)(n * 66 + yt) * 66 * 256);
        #pragma unroll
        for (int it = 0; it < 5; ++it) {
            int ch = t + it * 256;
            if (ch < 1056) {
                int xt = ch >> 4, u = ch & 15;
                uint4 val = make_uint4(0u, 0u, 0u, 0u);
                if (interior && xt >= 1 && xt <= 64) {
                    int row = xt - 1;
                    val = *(const uint4*)&xs[row * 64 + 4 * (u ^ ((row >> 2) & 3))];
                }
                dst[ch] = val;
            }
        }
    } else {
        // ---- w path: w[k][c][tap] fp32 -> wb2 frag-ordered ----
        const int kg = b - 1056;                       // this block's out-channel k
        for (int e = t; e < 1152; e += 256) lw[e] = w[kg * 1152 + e];
        __syncthreads();
        const int basek = (kg >> 5) * 1024 + (kg & 31) * 8;   // kgrp*1024 + klocal*8
        #pragma unroll
        for (int tap = 0; tap < 9; ++tap) {
            if (t < 128) {
                int c = t;
                int idx = (tap * 4 + (c >> 5)) * 8192 + basek
                        + ((c >> 4) & 1) * 512 + ((c >> 3) & 1) * 256 + (c & 7);
                wb[idx] = __float2bfloat16(lw[c * 9 + tap]);
            }
        }
    }
}

// ---------------- main conv: 2-row X tile, 2 blocks/CU, 4 waves/SIMD ------------------
// Block: (n, y-pair) -> 256 k x 128 m (2 y x 64 x). 8 waves (4k x 2m), each 64k x 64m.
// Per chunk per wave: 4 W global loads (1 chunk ahead, ping-pong) + 4 X ds_reads +
// 8 MFMA. No barriers after prologue; TLP (4 waves/SIMD) hides load phases.
#define DO_CHUNK(J, AUSE, ALOAD, RS66)                                                        \
  {                                                                                           \
    int jn = (J) + 1; if (jn >= 36) jn = 0;                                                   \
    const char* wc = wgw + (size_t)jn * 16384;                                                \
    _Pragma("unroll") for (int kf = 0; kf < 2; ++kf)                                          \
      _Pragma("unroll") for (int ks = 0; ks < 2; ++ks)                                        \
        ALOAD[kf][ks] = *(const bf16x8*)(wc + kf * 2048 + ks * 1024);                         \
    const int cc_ = (J) & 3;                                                                  \
    _Pragma("unroll") for (int ks = 0; ks < 2; ++ks) {                                        \
      bf16x8 xv[2];                                                                           \
      _Pragma("unroll") for (int f = 0; f < 2; ++f) {                                         \
        int rc  = rc0[f] + (RS66);                                                            \
        int off = cc_ * 64 + ks * 32 + hi4;                                                   \
        xv[f] = *(const bf16x8*)(lds + rc * 256 + (off ^ ((rc & 7) << 4)));                   \
      }                                                                                       \
      __builtin_amdgcn_s_setprio(1);                                                          \
      _Pragma("unroll") for (int kf = 0; kf < 2; ++kf)                                        \
        _Pragma("unroll") for (int f = 0; f < 2; ++f)                                         \
          acc[kf][f] = __builtin_amdgcn_mfma_f32_32x32x16_bf16(AUSE[kf][ks], xv[f],           \
                                                               acc[kf][f], 0, 0, 0);         \
      __builtin_amdgcn_s_setprio(0);                                                          \
    }                                                                                         \
  }

__global__ __launch_bounds__(512, 4)
void conv3x3_mfma_kernel(const char* __restrict__ xg,
                         const char* __restrict__ wg2,
                         float* __restrict__ out) {
    __shared__ uint4 smem[LDSX_BYTES / 16];
    char* lds = (char*)smem;

    const int t    = threadIdx.x;
    const int b    = blockIdx.x;        // 0..511
    const int yp   = b & 31;            // y-pair index
    const int n    = b >> 5;
    const int lane = t & 63;
    const int wv   = t >> 6;
    const int lm   = lane & 31;
    const int hi   = lane >> 5;
    const int kb   = (wv & 3) * 64;     // wave k-base (0/64/128/192)
    const int mb   = (wv >> 2) * 64;    // wave m-base (0/64)
    const int hi4  = hi * 16;

    int rc0[2];
    #pragma unroll
    for (int f = 0; f < 2; ++f) {
        int m = mb + f * 32 + lm;
        rc0[f] = (m >> 6) * 66 + (m & 63);
    }

    // ---- prologue: stage X rows [yp*2 .. yp*2+3] (linear dest, pre-swizzled src) ----
    const char* xsrc = xg + (size_t)(n * 66 + yp * 2) * 66 * 256;
    for (int ch = t; ch < LDSX_BYTES / 16; ch += 512) {
        int L = ch * 16;
        gload16(lds + L, xsrc + (L ^ (((L >> 8) & 7) << 4)));
    }

    // ---- prologue: W chunk 0 into register set A (coalesced, frag-linear layout) ----
    const char* wgw = wg2 + (kb >> 5) * 2048 + lane * 16;
    bf16x8 aA[2][2], aB[2][2];
    #pragma unroll
    for (int kf = 0; kf < 2; ++kf)
        #pragma unroll
        for (int ks = 0; ks < 2; ++ks)
            aA[kf][ks] = *(const bf16x8*)(wgw + kf * 2048 + ks * 1024);

    asm volatile("s_waitcnt vmcnt(0)" ::: "memory");
    __syncthreads();                    // X tile staged; only barrier in the kernel

    f32x16 acc[2][2];
    #pragma unroll
    for (int i = 0; i < 2; ++i)
        #pragma unroll
        for (int j = 0; j < 2; ++j)
            acc[i][j] = (f32x16)(0.f);

    for (int tap = 0; tap < 9; ++tap) {
        const int r    = (tap >= 6) ? 2 : (tap >= 3 ? 1 : 0);
        const int rs66 = r * 66 + (tap - r * 3);
        const int j0   = tap * 4;
        DO_CHUNK(j0 + 0, aA, aB, rs66)
        DO_CHUNK(j0 + 1, aB, aA, rs66)
        DO_CHUNK(j0 + 2, aA, aB, rs66)
        DO_CHUNK(j0 + 3, aB, aA, rs66)
    }

    // ---- epilogue: D row(k) = (reg&3)+8*(reg>>2)+4*hi, col(m) = lm ----
    const int y0 = yp * 2;
    #pragma unroll
    for (int kf = 0; kf < 2; ++kf) {
        const int kbase2 = kb + kf * 32 + 4 * hi;
        #pragma unroll
        for (int f = 0; f < 2; ++f) {
            int m  = mb + f * 32 + lm;
            int yy = m >> 6;
            int xx = m & 63;
            float* op = out + (((size_t)(n * 256 + kbase2) * 64) + y0 + yy) * 64 + xx;
            #pragma unroll
            for (int reg = 0; reg < 16; ++reg) {
                int koff = (reg & 3) + 8 * (reg >> 2);
                op[(size_t)koff * 4096] = acc[kf][f][reg];
            }
        }
    }
}

// ---------------- fallback (fp32, known-correct) ----------------
__global__ __launch_bounds__(256, 3)
void conv3x3_f32_kernel(const float* __restrict__ x,
                        const float* __restrict__ w,
                        float* __restrict__ out) {
    __shared__ float xs[16][3][72];
    __shared__ float ws[16][9][64];

    const int t  = threadIdx.x;
    const int kt = blockIdx.x & 3;
    const int y  = (blockIdx.x >> 2) & 63;
    const int n  = blockIdx.x >> 8;

    const int k2   = t >> 3;
    const int xg   = t & 7;
    const int kloc = k2 * 2;
    const int x0   = xg * 8;

    float acc0[8] = {0.f,0.f,0.f,0.f,0.f,0.f,0.f,0.f};
    float acc1[8] = {0.f,0.f,0.f,0.f,0.f,0.f,0.f,0.f};

    const int k0 = kt * 64;

    for (int c0 = 0; c0 < C_IN; c0 += 16) {
        for (int idx = t; idx < 16 * 3 * 66; idx += 256) {
            int col = idx % 66;
            int rc  = idx / 66;
            int r   = rc % 3;
            int c   = rc / 3;
            int gx  = col - 1;
            int gy  = y - 1 + r;
            float v = 0.f;
            if ((unsigned)gx < (unsigned)W_IMG && (unsigned)gy < (unsigned)H_IMG)
                v = x[(((n * C_IN) + c0 + c) * H_IMG + gy) * W_IMG + gx];
            xs[c][r][col] = v;
        }
        for (int idx = t; idx < 64 * 16 * 9; idx += 256) {
            int tap = idx % 9;
            int ck  = idx / 9;
            int c   = ck % 16;
            int k   = ck / 16;
            ws[c][tap][k] = w[((k0 + k) * C_IN + c0 + c) * 9 + tap];
        }
        __syncthreads();

        #pragma unroll 2
        for (int c = 0; c < 16; ++c) {
            #pragma unroll
            for (int r = 0; r < 3; ++r) {
                float xr[10];
                #pragma unroll
                for (int i = 0; i < 10; ++i) xr[i] = xs[c][r][x0 + i];
                #pragma unroll
                for (int s = 0; s < 3; ++s) {
                    float w0 = ws[c][r * 3 + s][kloc];
                    float w1 = ws[c][r * 3 + s][kloc + 1];
                    #pragma unroll
                    for (int i = 0; i < 8; ++i) {
                        acc0[i] = fmaf(w0, xr[i + s], acc0[i]);
                        acc1[i] = fmaf(w1, xr[i + s], acc1[i]);
                    }
                }
            }
        }
        __syncthreads();
    }

    float* o0 = &out[(((n * K_OUT) + k0 + kloc) * H_IMG + y) * W_IMG + x0];
    float* o1 = o0 + H_IMG * W_IMG;
    #pragma unroll
    for (int i = 0; i < 8; ++i) o0[i] = acc0[i];
    #pragma unroll
    for (int i = 0; i < 8; ++i) o1[i] = acc1[i];
}

extern "C" void kernel_launch(void* const* d_in, const int* in_sizes, int n_in,
                              void* d_out, int out_size, void* d_ws, size_t ws_size,
                              hipStream_t stream) {
    const float* x = (const float*)d_in[0];
    const float* w = (const float*)d_in[1];
    float* out = (float*)d_out;
    (void)in_sizes; (void)n_in; (void)out_size;

    if (ws_size >= WS_NEED) {
        __hip_bfloat16* xb = (__hip_bfloat16*)d_ws;
        __hip_bfloat16* wb = (__hip_bfloat16*)((char*)d_ws + XB_BYTES);
        transform_fused_kernel<<<1056 + 256, 256, 0, stream>>>(x, w, xb, wb);
        conv3x3_mfma_kernel<<<512, 512, 0, stream>>>((const char*)xb, (const char*)wb, out);
    } else {
        conv3x3_f32_kernel<<<4096, 256, 0, stream>>>(x, w, out);
    }
}

// Round 8
// 130.917 us; speedup vs baseline: 1.0140x; 1.0140x over previous
//
#include <hip/hip_runtime.h>
#include <hip/hip_bf16.h>
#include <stdint.h>

typedef short bf16x8 __attribute__((ext_vector_type(8)));
typedef float f32x16 __attribute__((ext_vector_type(16)));

#define N_IMG 16
#define C_IN  128
#define H_IMG 64
#define W_IMG 64
#define K_OUT 256

// ws layout: xb = padded NHWC bf16 [16][66][66][128]; wb2 = frag-ordered W bf16:
//   [chunk=tap*4+cc (36)][kgrp (8)][ks (2)][lane (64)][8 bf16]   (16 KB per chunk)
#define XB_BYTES (16ull*66*66*128*2)       // 17,842,176
#define WB_BYTES (36ull*8*2*64*16)         //    589,824
#define WS_NEED  (XB_BYTES + WB_BYTES)

#define LDSX_BYTES (4*66*256)              // 67,584 (X tile: 2 out-rows + halo)

__device__ __forceinline__ void gload16(void* lds, const void* g) {
    __builtin_amdgcn_global_load_lds(
        (const __attribute__((address_space(1))) void*)g,
        (__attribute__((address_space(3))) void*)lds, 16, 0, 0);
}

__device__ __forceinline__ uint32_t pack2(float a, float b) {
    __hip_bfloat16 ha = __float2bfloat16(a), hb = __float2bfloat16(b);
    return (uint32_t)*(uint16_t*)&ha | ((uint32_t)*(uint16_t*)&hb << 16);
}

// ---------------- fused prep: x -> padded NHWC bf16, w -> frag-ordered wb2 ------------
// blocks [0,1056): x rows.  blocks [1056,1312): w out-channel groups (one k each).
__global__ __launch_bounds__(256)
void transform_fused_kernel(const float* __restrict__ x, const float* __restrict__ w,
                            __hip_bfloat16* __restrict__ xb, __hip_bfloat16* __restrict__ wb) {
    __shared__ __align__(16) uint32_t xs[64 * 64];   // [row=x][cpair j], XOR-swizzled
    __shared__ float lw[1152];
    const int b = blockIdx.x;
    const int t = threadIdx.x;

    if (b < 1056) {
        const int yt = b % 66;
        const int n  = b / 66;
        const bool interior = (yt >= 1 && yt <= 64);

        if (interior) {
            const float4* src = (const float4*)(x + (size_t)n * 524288 + (size_t)(yt - 1) * 64);
            #pragma unroll
            for (int it = 0; it < 4; ++it) {
                const int x4 = t & 15;                 // float4 index in row (coalesced)
                const int j  = (t >> 4) + it * 16;     // c-pair 0..63
                float4 va = src[(2 * j) * 1024 + x4];
                float4 vb = src[(2 * j + 1) * 1024 + x4];
                const float* pa = (const float*)&va;
                const float* pb = (const float*)&vb;
                #pragma unroll
                for (int i = 0; i < 4; ++i) {
                    int row = x4 * 4 + i;
                    xs[row * 64 + (j ^ (((row >> 2) & 3) << 2))] = pack2(pa[i], pb[i]);
                }
            }
        }
        __syncthreads();

        uint4* dst = (uint4*)((char*)xb + (size_t)(n * 66 + yt) * 66 * 256);
        #pragma unroll
        for (int it = 0; it < 5; ++it) {
            int ch = t + it * 256;
            if (ch < 1056) {
                int xt = ch >> 4, u = ch & 15;
                uint4 val = make_uint4(0u, 0u, 0u, 0u);
                if (interior && xt >= 1 && xt <= 64) {
                    int row = xt - 1;
                    val = *(const uint4*)&xs[row * 64 + 4 * (u ^ ((row >> 2) & 3))];
                }
                dst[ch] = val;
            }
        }
    } else {
        // ---- w path: w[k][c][tap] fp32 -> wb2 frag-ordered ----
        const int kg = b - 1056;                       // this block's out-channel k
        for (int e = t; e < 1152; e += 256) lw[e] = w[kg * 1152 + e];
        __syncthreads();
        const int basek = (kg >> 5) * 1024 + (kg & 31) * 8;   // kgrp*1024 + klocal*8
        #pragma unroll
        for (int tap = 0; tap < 9; ++tap) {
            if (t < 128) {
                int c = t;
                int idx = (tap * 4 + (c >> 5)) * 8192 + basek
                        + ((c >> 4) & 1) * 512 + ((c >> 3) & 1) * 256 + (c & 7);
                wb[idx] = __float2bfloat16(lw[c * 9 + tap]);
            }
        }
    }
}

// ---------------- main conv: staggered barrier-free K-loop ---------------------------
// Block: (n, y-pair) -> 256 k x 128 m. 8 waves (4k x 2m), each 64k x 64m.
// Each wave walks the 36-chunk ring starting at wv*4+(wv>>1) -> waves permanently
// phase-shifted so LDS-read / W-load / MFMA phases overlap across waves.
#define LOADW(DST, JJ)                                                    \
  { const char* wc = wgw + (size_t)(JJ) * 16384;                          \
    _Pragma("unroll") for (int kf = 0; kf < 2; ++kf)                      \
      _Pragma("unroll") for (int ks = 0; ks < 2; ++ks)                    \
        DST[kf][ks] = *(const bf16x8*)(wc + kf * 2048 + ks * 1024); }

#define COMPUTE(JJ, AU)                                                   \
  {                                                                       \
    const int tap_ = (JJ) >> 2, cc_ = (JJ) & 3;                           \
    const int r_   = (tap_ >= 6) ? 2 : ((tap_ >= 3) ? 1 : 0);             \
    const int rs66 = tap_ + r_ * 63;          /* r*66 + s */              \
    const int scc  = hi4 ^ (cc_ << 6);                                    \
    bf16x8 xv0[2], xv1[2];                                                \
    _Pragma("unroll") for (int f = 0; f < 2; ++f) {                       \
      int rc = rc0[f] + rs66;                                             \
      int Lb = rc * 256 + (scc ^ ((rc & 15) << 4));                       \
      xv0[f] = *(const bf16x8*)(lds + Lb);                                \
      xv1[f] = *(const bf16x8*)(lds + (Lb ^ 32));                         \
    }                                                                     \
    __builtin_amdgcn_s_setprio(1);                                        \
    _Pragma("unroll") for (int kf = 0; kf < 2; ++kf)                      \
      _Pragma("unroll") for (int f = 0; f < 2; ++f)                       \
        acc[kf][f] = __builtin_amdgcn_mfma_f32_32x32x16_bf16(AU[kf][0], xv0[f], acc[kf][f], 0, 0, 0); \
    _Pragma("unroll") for (int kf = 0; kf < 2; ++kf)                      \
      _Pragma("unroll") for (int f = 0; f < 2; ++f)                       \
        acc[kf][f] = __builtin_amdgcn_mfma_f32_32x32x16_bf16(AU[kf][1], xv1[f], acc[kf][f], 0, 0, 0); \
    __builtin_amdgcn_s_setprio(0);                                        \
  }

__global__ __launch_bounds__(512, 4)
void conv3x3_mfma_kernel(const char* __restrict__ xg,
                         const char* __restrict__ wg2,
                         float* __restrict__ out) {
    __shared__ uint4 smem[LDSX_BYTES / 16];
    char* lds = (char*)smem;

    const int t    = threadIdx.x;
    const int b0   = blockIdx.x;
    const int b    = ((b0 & 7) << 6) | (b0 >> 3);   // XCD-bijective remap (512 = 8*64)
    const int yp   = b & 31;            // y-pair index
    const int n    = b >> 5;
    const int lane = t & 63;
    const int wv   = t >> 6;
    const int lm   = lane & 31;
    const int hi   = lane >> 5;
    const int kb   = (wv & 3) * 64;     // wave k-base (0/64/128/192)
    const int mb   = (wv >> 2) * 64;    // wave m-base (0/64)
    const int hi4  = hi * 16;

    int rc0[2];
    #pragma unroll
    for (int f = 0; f < 2; ++f) {
        int m = mb + f * 32 + lm;
        rc0[f] = (m >> 6) * 66 + (m & 63);
    }

    // ---- prologue: stage X rows [yp*2 .. yp*2+3] (linear dest, pre-swizzled src) ----
    const char* xsrc = xg + (size_t)(n * 66 + yp * 2) * 66 * 256;
    for (int ch = t; ch < LDSX_BYTES / 16; ch += 512) {
        int L = ch * 16;
        gload16(lds + L, xsrc + (L ^ (((L >> 8) & 15) << 4)));
    }

    // ---- prologue: W chunk `start` into register set A (frag-linear layout) ----
    const char* wgw = wg2 + (wv & 3) * 4096 + lane * 16;
    const int start = wv * 4 + (wv >> 1);    // 0,4,9,13,18,22,27,31
    bf16x8 aA[2][2], aB[2][2];
    LOADW(aA, start)

    asm volatile("s_waitcnt vmcnt(0)" ::: "memory");
    __syncthreads();                    // X tile staged; only barrier in the kernel

    f32x16 acc[2][2];
    #pragma unroll
    for (int i = 0; i < 2; ++i)
        #pragma unroll
        for (int j = 0; j < 2; ++j)
            acc[i][j] = (f32x16)(0.f);

    int j  = start;
    int jn = (j + 1 == 36) ? 0 : j + 1;
    for (int it = 0; it < 18; ++it) {
        LOADW(aB, jn)
        COMPUTE(j, aA)
        j = jn; jn = (j + 1 == 36) ? 0 : j + 1;
        LOADW(aA, jn)
        COMPUTE(j, aB)
        j = jn; jn = (j + 1 == 36) ? 0 : j + 1;
    }

    // ---- epilogue: D row(k) = (reg&3)+8*(reg>>2)+4*hi, col(m) = lm ----
    const int y0 = yp * 2;
    #pragma unroll
    for (int kf = 0; kf < 2; ++kf) {
        const int kbase2 = kb + kf * 32 + 4 * hi;
        #pragma unroll
        for (int f = 0; f < 2; ++f) {
            int m  = mb + f * 32 + lm;
            int yy = m >> 6;
            int xx = m & 63;
            float* op = out + (((size_t)(n * 256 + kbase2) * 64) + y0 + yy) * 64 + xx;
            #pragma unroll
            for (int reg = 0; reg < 16; ++reg) {
                int koff = (reg & 3) + 8 * (reg >> 2);
                op[(size_t)koff * 4096] = acc[kf][f][reg];
            }
        }
    }
}

// ---------------- fallback (fp32, known-correct) ----------------
__global__ __launch_bounds__(256, 3)
void conv3x3_f32_kernel(const float* __restrict__ x,
                        const float* __restrict__ w,
                        float* __restrict__ out) {
    __shared__ float xs[16][3][72];
    __shared__ float ws[16][9][64];

    const int t  = threadIdx.x;
    const int kt = blockIdx.x & 3;
    const int y  = (blockIdx.x >> 2) & 63;
    const int n  = blockIdx.x >> 8;

    const int k2   = t >> 3;
    const int xg   = t & 7;
    const int kloc = k2 * 2;
    const int x0   = xg * 8;

    float acc0[8] = {0.f,0.f,0.f,0.f,0.f,0.f,0.f,0.f};
    float acc1[8] = {0.f,0.f,0.f,0.f,0.f,0.f,0.f,0.f};

    const int k0 = kt * 64;

    for (int c0 = 0; c0 < C_IN; c0 += 16) {
        for (int idx = t; idx < 16 * 3 * 66; idx += 256) {
            int col = idx % 66;
            int rc  = idx / 66;
            int r   = rc % 3;
            int c   = rc / 3;
            int gx  = col - 1;
            int gy  = y - 1 + r;
            float v = 0.f;
            if ((unsigned)gx < (unsigned)W_IMG && (unsigned)gy < (unsigned)H_IMG)
                v = x[(((n * C_IN) + c0 + c) * H_IMG + gy) * W_IMG + gx];
            xs[c][r][col] = v;
        }
        for (int idx = t; idx < 64 * 16 * 9; idx += 256) {
            int tap = idx % 9;
            int ck  = idx / 9;
            int c   = ck % 16;
            int k   = ck / 16;
            ws[c][tap][k] = w[((k0 + k) * C_IN + c0 + c) * 9 + tap];
        }
        __syncthreads();

        #pragma unroll 2
        for (int c = 0; c < 16; ++c) {
            #pragma unroll
            for (int r = 0; r < 3; ++r) {
                float xr[10];
                #pragma unroll
                for (int i = 0; i < 10; ++i) xr[i] = xs[c][r][x0 + i];
                #pragma unroll
                for (int s = 0; s < 3; ++s) {
                    float w0 = ws[c][r * 3 + s][kloc];
                    float w1 = ws[c][r * 3 + s][kloc + 1];
                    #pragma unroll
                    for (int i = 0; i < 8; ++i) {
                        acc0[i] = fmaf(w0, xr[i + s], acc0[i]);
                        acc1[i] = fmaf(w1, xr[i + s], acc1[i]);
                    }
                }
            }
        }
        __syncthreads();
    }

    float* o0 = &out[(((n * K_OUT) + k0 + kloc) * H_IMG + y) * W_IMG + x0];
    float* o1 = o0 + H_IMG * W_IMG;
    #pragma unroll
    for (int i = 0; i < 8; ++i) o0[i] = acc0[i];
    #pragma unroll
    for (int i = 0; i < 8; ++i) o1[i] = acc1[i];
}

extern "C" void kernel_launch(void* const* d_in, const int* in_sizes, int n_in,
                              void* d_out, int out_size, void* d_ws, size_t ws_size,
                              hipStream_t stream) {
    const float* x = (const float*)d_in[0];
    const float* w = (const float*)d_in[1];
    float* out = (float*)d_out;
    (void)in_sizes; (void)n_in; (void)out_size;

    if (ws_size >= WS_NEED) {
        __hip_bfloat16* xb = (__hip_bfloat16*)d_ws;
        __hip_bfloat16* wb = (__hip_bfloat16*)((char*)d_ws + XB_BYTES);
        transform_fused_kernel<<<1056 + 256, 256, 0, stream>>>(x, w, xb, wb);
        conv3x3_mfma_kernel<<<512, 512, 0, stream>>>((const char*)xb, (const char*)wb, out);
    } else {
        conv3x3_f32_kernel<<<4096, 256, 0, stream>>>(x, w, out);
    }
}

// Round 11
// 127.737 us; speedup vs baseline: 1.0392x; 1.0249x over previous
//
#include <hip/hip_runtime.h>
#include <hip/hip_bf16.h>
#include <stdint.h>

typedef short bf16x8 __attribute__((ext_vector_type(8)));
typedef float f32x16 __attribute__((ext_vector_type(16)));

#define N_IMG 16
#define C_IN  128
#define H_IMG 64
#define W_IMG 64
#define K_OUT 256

// ws layout: xb = padded NHWC bf16 [16][66][66][128]; wb2 = frag-ordered W bf16:
//   [chunk=tap*4+cc (36)][kgrp (8)][ks (2)][lane (64)][8 bf16]   (16 KB per chunk)
#define XB_BYTES (16ull*66*66*128*2)       // 17,842,176
#define WB_BYTES (36ull*8*2*64*16)         //    589,824
#define WS_NEED  (XB_BYTES + WB_BYTES)

#define LDSX_BYTES (4*66*256)              // 67,584 (X tile: 2 out-rows + halo)

__device__ __forceinline__ void gload16(void* lds, const void* g) {
    __builtin_amdgcn_global_load_lds(
        (const __attribute__((address_space(1))) void*)g,
        (__attribute__((address_space(3))) void*)lds, 16, 0, 0);
}

__device__ __forceinline__ uint32_t pack2(float a, float b) {
    __hip_bfloat16 ha = __float2bfloat16(a), hb = __float2bfloat16(b);
    return (uint32_t)*(uint16_t*)&ha | ((uint32_t)*(uint16_t*)&hb << 16);
}

// ---------------- fused prep: x -> padded NHWC bf16, w -> frag-ordered wb2 ------------
// blocks [0,1056): x rows.  blocks [1056,1312): w out-channel groups (one k each).
__global__ __launch_bounds__(256)
void transform_fused_kernel(const float* __restrict__ x, const float* __restrict__ w,
                            __hip_bfloat16* __restrict__ xb, __hip_bfloat16* __restrict__ wb) {
    __shared__ __align__(16) uint32_t xs[64 * 64];   // [row=x][cpair j], XOR-swizzled
    __shared__ float lw[1152];
    const int b = blockIdx.x;
    const int t = threadIdx.x;

    if (b < 1056) {
        const int yt = b % 66;
        const int n  = b / 66;
        const bool interior = (yt >= 1 && yt <= 64);

        if (interior) {
            const float4* src = (const float4*)(x + (size_t)n * 524288 + (size_t)(yt - 1) * 64);
            #pragma unroll
            for (int it = 0; it < 4; ++it) {
                const int x4 = t & 15;                 // float4 index in row (coalesced)
                const int j  = (t >> 4) + it * 16;     // c-pair 0..63
                float4 va = src[(2 * j) * 1024 + x4];
                float4 vb = src[(2 * j + 1) * 1024 + x4];
                const float* pa = (const float*)&va;
                const float* pb = (const float*)&vb;
                #pragma unroll
                for (int i = 0; i < 4; ++i) {
                    int row = x4 * 4 + i;
                    xs[row * 64 + (j ^ (((row >> 2) & 3) << 2))] = pack2(pa[i], pb[i]);
                }
            }
        }
        __syncthreads();

        uint4* dst = (uint4*)((char*)xb + (size_t)(n * 66 + yt) * 66 * 256);
        #pragma unroll
        for (int it = 0; it < 5; ++it) {
            int ch = t + it * 256;
            if (ch < 1056) {
                int xt = ch >> 4, u = ch & 15;
                uint4 val = make_uint4(0u, 0u, 0u, 0u);
                if (interior && xt >= 1 && xt <= 64) {
                    int row = xt - 1;
                    val = *(const uint4*)&xs[row * 64 + 4 * (u ^ ((row >> 2) & 3))];
                }
                dst[ch] = val;
            }
        }
    } else {
        // ---- w path: w[k][c][tap] fp32 -> wb2 frag-ordered ----
        const int kg = b - 1056;                       // this block's out-channel k
        for (int e = t; e < 1152; e += 256) lw[e] = w[kg * 1152 + e];
        __syncthreads();
        const int basek = (kg >> 5) * 1024 + (kg & 31) * 8;   // kgrp*1024 + klocal*8
        #pragma unroll
        for (int tap = 0; tap < 9; ++tap) {
            if (t < 128) {
                int c = t;
                int idx = (tap * 4 + (c >> 5)) * 8192 + basek
                        + ((c >> 4) & 1) * 512 + ((c >> 3) & 1) * 256 + (c & 7);
                wb[idx] = __float2bfloat16(lw[c * 9 + tap]);
            }
        }
    }
}

// ---------------- main conv: 64k x 128m waves, static unrolled K-loop ----------------
// Block: 256k x 128m (y-pair), 4 waves (k-split), 256 thr; 2 blocks/CU.
// Wave = 64k x 128m: 16 MFMA per 32c chunk fed by 4 KB W (3-deep register ring
// prefetch from global/L2) + 8 KB X ds_reads. W bytes/MFMA = 0.25 KB
// (half of R8) — attacks the measured ~20 B/cyc/CU vmem-fill wall.
#define LOADW(DST, JJ)                                                     \
  { const char* wc_ = wgw + (size_t)(JJ) * 16384;                          \
    _Pragma("unroll") for (int kf_ = 0; kf_ < 2; ++kf_)                    \
      _Pragma("unroll") for (int ks_ = 0; ks_ < 2; ++ks_)                  \
        DST[kf_][ks_] = *(const bf16x8*)(wc_ + kf_ * 2048 + ks_ * 1024); }

__global__ __launch_bounds__(256, 2)
void conv3x3_mfma_kernel(const char* __restrict__ xg,
                         const char* __restrict__ wg2,
                         float* __restrict__ out) {
    __shared__ uint4 smem[LDSX_BYTES / 16];
    char* lds = (char*)smem;

    const int t    = threadIdx.x;
    const int b0   = blockIdx.x;
    const int b    = ((b0 & 7) << 6) | (b0 >> 3);   // XCD-bijective remap (512 = 8*64)
    const int yp   = b & 31;            // y-pair index
    const int n    = b >> 5;
    const int lane = t & 63;
    const int wv   = t >> 6;            // 0..3
    const int lm   = lane & 31;
    const int hi   = lane >> 5;
    const int kb   = wv * 64;           // wave k-base
    const int hi4  = hi * 16;

    int rc0[4];
    #pragma unroll
    for (int f = 0; f < 4; ++f) {
        int m = f * 32 + lm;            // m = (yy,xx) over 2 y-rows x 64 x
        rc0[f] = (m >> 6) * 66 + (m & 63);
    }

    // ---- prologue: stage X rows [yp*2 .. yp*2+3] (linear dest, pre-swizzled src) ----
    const char* xsrc = xg + (size_t)(n * 66 + yp * 2) * 66 * 256;
    for (int ch = t; ch < LDSX_BYTES / 16; ch += 256) {
        int L = ch * 16;
        gload16(lds + L, xsrc + (L ^ (((L >> 8) & 15) << 4)));
    }

    // ---- prologue: W chunks 0,1 into register ring ----
    const char* wgw = wg2 + wv * 4096 + lane * 16;
    bf16x8 aA[2][2], aB[2][2], aC[2][2];
    LOADW(aA, 0)
    LOADW(aB, 1)

    asm volatile("s_waitcnt vmcnt(0)" ::: "memory");
    __syncthreads();                    // X tile staged; only barrier in the kernel

    f32x16 acc[2][4];
    #pragma unroll
    for (int i = 0; i < 2; ++i)
        #pragma unroll
        for (int jj = 0; jj < 4; ++jj)
            acc[i][jj] = (f32x16)(0.f);

    #pragma unroll
    for (int tap = 0; tap < 9; ++tap) {
        const int r    = (tap >= 6) ? 2 : ((tap >= 3) ? 1 : 0);
        const int rs66 = r * 66 + (tap - r * 3);
        int base[4];
        #pragma unroll
        for (int f = 0; f < 4; ++f) {
            int rc = rc0[f] + rs66;
            base[f] = rc * 256 + (hi4 ^ ((rc & 15) << 4));
        }
        #pragma unroll
        for (int cc = 0; cc < 4; ++cc) {
            const int j   = tap * 4 + cc;            // compile-time
            const int jp2 = (j + 2 >= 36) ? (j + 2 - 36) : (j + 2);
            bf16x8 (*AU)[2] = (j % 3 == 0) ? aA : ((j % 3 == 1) ? aB : aC);
            bf16x8 (*AL)[2] = ((j + 2) % 3 == 0) ? aA : (((j + 2) % 3 == 1) ? aB : aC);
            // prefetch W chunk j+2 into ring slot (tail wraps -> harmless reload)
            {
                const char* wc_ = wgw + (size_t)jp2 * 16384;
                #pragma unroll
                for (int kf = 0; kf < 2; ++kf)
                    #pragma unroll
                    for (int ks = 0; ks < 2; ++ks)
                        AL[kf][ks] = *(const bf16x8*)(wc_ + kf * 2048 + ks * 1024);
            }
            // compute chunk j
            #pragma unroll
            for (int ks = 0; ks < 2; ++ks) {
                bf16x8 xv[4];
                #pragma unroll
                for (int f = 0; f < 4; ++f)
                    xv[f] = *(const bf16x8*)(lds + (base[f] ^ (cc << 6) ^ (ks << 5)));
                __builtin_amdgcn_s_setprio(1);
                #pragma unroll
                for (int kf = 0; kf < 2; ++kf)
                    #pragma unroll
                    for (int f = 0; f < 4; ++f)
                        acc[kf][f] = __builtin_amdgcn_mfma_f32_32x32x16_bf16(
                            AU[kf][ks], xv[f], acc[kf][f], 0, 0, 0);
                __builtin_amdgcn_s_setprio(0);
            }
        }
    }

    // ---- epilogue: D row(k) = (reg&3)+8*(reg>>2)+4*hi, col(m) = lm ----
    const int y0 = yp * 2;
    #pragma unroll
    for (int kf = 0; kf < 2; ++kf) {
        const int kbase2 = kb + kf * 32 + 4 * hi;
        #pragma unroll
        for (int f = 0; f < 4; ++f) {
            int m  = f * 32 + lm;
            int yy = m >> 6;
            int xx = m & 63;
            float* op = out + (((size_t)(n * 256 + kbase2) * 64) + y0 + yy) * 64 + xx;
            #pragma unroll
            for (int reg = 0; reg < 16; ++reg) {
                int koff = (reg & 3) + 8 * (reg >> 2);
                op[(size_t)koff * 4096] = acc[kf][f][reg];
            }
        }
    }
}

// ---------------- fallback (fp32, known-correct) ----------------
__global__ __launch_bounds__(256, 3)
void conv3x3_f32_kernel(const float* __restrict__ x,
                        const float* __restrict__ w,
                        float* __restrict__ out) {
    __shared__ float xs[16][3][72];
    __shared__ float ws[16][9][64];

    const int t  = threadIdx.x;
    const int kt = blockIdx.x & 3;
    const int y  = (blockIdx.x >> 2) & 63;
    const int n  = blockIdx.x >> 8;

    const int k2   = t >> 3;
    const int xg   = t & 7;
    const int kloc = k2 * 2;
    const int x0   = xg * 8;

    float acc0[8] = {0.f,0.f,0.f,0.f,0.f,0.f,0.f,0.f};
    float acc1[8] = {0.f,0.f,0.f,0.f,0.f,0.f,0.f,0.f};

    const int k0 = kt * 64;

    for (int c0 = 0; c0 < C_IN; c0 += 16) {
        for (int idx = t; idx < 16 * 3 * 66; idx += 256) {
            int col = idx % 66;
            int rc  = idx / 66;
            int r   = rc % 3;
            int c   = rc / 3;
            int gx  = col - 1;
            int gy  = y - 1 + r;
            float v = 0.f;
            if ((unsigned)gx < (unsigned)W_IMG && (unsigned)gy < (unsigned)H_IMG)
                v = x[(((n * C_IN) + c0 + c) * H_IMG + gy) * W_IMG + gx];
            xs[c][r][col] = v;
        }
        for (int idx = t; idx < 64 * 16 * 9; idx += 256) {
            int tap = idx % 9;
            int ck  = idx / 9;
            int c   = ck % 16;
            int k   = ck / 16;
            ws[c][tap][k] = w[((k0 + k) * C_IN + c0 + c) * 9 + tap];
        }
        __syncthreads();

        #pragma unroll 2
        for (int c = 0; c < 16; ++c) {
            #pragma unroll
            for (int r = 0; r < 3; ++r) {
                float xr[10];
                #pragma unroll
                for (int i = 0; i < 10; ++i) xr[i] = xs[c][r][x0 + i];
                #pragma unroll
                for (int s = 0; s < 3; ++s) {
                    float w0 = ws[c][r * 3 + s][kloc];
                    float w1 = ws[c][r * 3 + s][kloc + 1];
                    #pragma unroll
                    for (int i = 0; i < 8; ++i) {
                        acc0[i] = fmaf(w0, xr[i + s], acc0[i]);
                        acc1[i] = fmaf(w1, xr[i + s], acc1[i]);
                    }
                }
            }
        }
        __syncthreads();
    }

    float* o0 = &out[(((n * K_OUT) + k0 + kloc) * H_IMG + y) * W_IMG + x0];
    float* o1 = o0 + H_IMG * W_IMG;
    #pragma unroll
    for (int i = 0; i < 8; ++i) o0[i] = acc0[i];
    #pragma unroll
    for (int i = 0; i < 8; ++i) o1[i] = acc1[i];
}

extern "C" void kernel_launch(void* const* d_in, const int* in_sizes, int n_in,
                              void* d_out, int out_size, void* d_ws, size_t ws_size,
                              hipStream_t stream) {
    const float* x = (const float*)d_in[0];
    const float* w = (const float*)d_in[1];
    float* out = (float*)d_out;
    (void)in_sizes; (void)n_in; (void)out_size;

    if (ws_size >= WS_NEED) {
        __hip_bfloat16* xb = (__hip_bfloat16*)d_ws;
        __hip_bfloat16* wb = (__hip_bfloat16*)((char*)d_ws + XB_BYTES);
        transform_fused_kernel<<<1056 + 256, 256, 0, stream>>>(x, w, xb, wb);
        conv3x3_mfma_kernel<<<512, 256, 0, stream>>>((const char*)xb, (const char*)wb, out);
    } else {
        conv3x3_f32_kernel<<<4096, 256, 0, stream>>>(x, w, out);
    }
}